// Round 26
// baseline (243.230 us; speedup 1.0000x reference)
//
#include <hip/hip_runtime.h>

#define N_NODES 100000
#define N_EDGES 3200000
#define D_FEAT  512
#define HIDDEN  16
#define NCLS    6
#define BSH     7                      // bucket = col >> 7
#define BNODES  128                    // nodes per bucket
#define NBUK    782                    // ceil(N_NODES/128)
#define BCAP    6144                   // LDS staging capacity in bsort
#define CAP     8192                   // fixed bucket capacity (mean 4092 + 64 sigma)
#define NBLK_A  512                    // scatter blocks: exactly 2 per CU
#define TILE    6250                   // ceil(N_EDGES/NBLK_A)
#define NGEMM   782                    // gemm tile blocks (128 rows each)
#define W1LD    522                    // W1T row stride in bf16 (512+10: stride 261w == 5 mod 32 -> 16 distinct bank starts)

// gemm smem layout (bytes): w1t[16*522]u16 = 16704 | xb0 16384 | xb1 16384
#define SM_W1   0
#define SM_XB0  16704
#define SM_XB1  33088
#define SM_SZ   49472

typedef __attribute__((ext_vector_type(8))) short bf16x8;
typedef __attribute__((ext_vector_type(4))) float f32x4;
typedef __attribute__((address_space(1))) const float gfloat;
typedef __attribute__((address_space(3))) float lfloat;

// ---------- helpers ----------

__device__ __forceinline__ int eidx(const int* __restrict__ ei, int is64, int pos) {
    return is64 ? ei[2 * (long long)pos] : ei[pos];
}

__global__ void k_detect(const int* __restrict__ ei, int* __restrict__ flag) {
    int v = ei[2 * threadIdx.x + 1];
    unsigned long long b = __ballot(v != 0);
    if (threadIdx.x == 0) flag[0] = (b == 0ULL) ? 1 : 0;
}

__device__ __forceinline__ unsigned short f2bf(float f) {     // RNE f32->bf16
    unsigned u = __float_as_uint(f);
    return (unsigned short)((u + 0x7FFFu + ((u >> 16) & 1u)) >> 16);
}

__device__ __forceinline__ unsigned cvtpk(float lo, float hi) {
    unsigned r;
    asm volatile("v_cvt_pk_bf16_f32 %0, %1, %2" : "=v"(r) : "v"(lo), "v"(hi));
    return r;
}

union bfrag {
    unsigned u[4];
    bf16x8   v;
};

// gemm body shared by fused and standalone kernels (R24 zero-VGPR staging +
// R25 both-sides XOR swizzle). R25 counters: conflicts halved, time flat ->
// LDS reads are NOT the critical path; buildA is latency/schedule bound.
__device__ __forceinline__ void gemm_body(char* smem, int bid, int t,
                                          const float* __restrict__ x,
                                          const float* __restrict__ W1g,
                                          unsigned short* __restrict__ h1b) {
    unsigned short* w1t = (unsigned short*)(smem + SM_W1);
    float* xb0 = (float*)(smem + SM_XB0);
    float* xb1 = (float*)(smem + SM_XB1);
    const int wid = t >> 6;
    const int L   = t & 63;
    const int lm  = L & 15;
    const int lk  = L >> 4;
    const int rowBase = bid * 128;

    for (int p = t; p < D_FEAT * HIDDEN; p += 256) {
        int k = p >> 4, j = p & 15;             // W1[k][j], coalesced read
        w1t[j * W1LD + k] = f2bf(W1g[p]);
    }

    // async stage of chunk s into buf: linear LDS dest (slot f = row*8+c),
    // global source PRE-SWIZZLED: slot (row,c) <- global quad c^(row&7).
#define STAGE(buf, s)                                                        \
    {                                                                        \
        _Pragma("unroll")                                                    \
        for (int it = 0; it < 4; ++it) {                                     \
            int f = it * 256 + t;                                            \
            int row = f >> 3, c = f & 7;                                     \
            int cs = c ^ (row & 7);                                          \
            int grow = min(rowBase + row, N_NODES - 1);                      \
            const float* gp = x + (size_t)grow * D_FEAT + (s) * 32 + cs * 4; \
            float* lp = (buf) + (size_t)(it * 256 + wid * 64) * 4;           \
            __builtin_amdgcn_global_load_lds((gfloat*)gp, (lfloat*)lp,       \
                                             16, 0, 0);                      \
        }                                                                    \
    }

    STAGE(xb0, 0);

    f32x4 accA = {0.0f, 0.0f, 0.0f, 0.0f};
    f32x4 accB = {0.0f, 0.0f, 0.0f, 0.0f};
    const int rA = wid * 32 + lm;              // lds row, tile A
    const int rB = rA + 16;                    // lds row, tile B
    const int qA0 = (lk * 2) ^ (rA & 7), qA1 = (lk * 2 + 1) ^ (rA & 7);
    const int qB0 = (lk * 2) ^ (rB & 7), qB1 = (lk * 2 + 1) ^ (rB & 7);
    const unsigned short* wrow = w1t + lm * W1LD + lk * 8;

#pragma unroll
    for (int s = 0; s < 16; ++s) {
        float* bcur = (s & 1) ? xb1 : xb0;     // compile-time (full unroll)
        float* bnxt = (s & 1) ? xb0 : xb1;
        __syncthreads();                       // drains vmcnt: bcur staged
        if (s < 15) STAGE(bnxt, s + 1);
        float4 a0 = *(const float4*)(bcur + rA * 32 + qA0 * 4);
        float4 a1 = *(const float4*)(bcur + rA * 32 + qA1 * 4);
        float4 b0 = *(const float4*)(bcur + rB * 32 + qB0 * 4);
        float4 b1 = *(const float4*)(bcur + rB * 32 + qB1 * 4);
        bfrag afA, afB;
        afA.u[0] = cvtpk(a0.x, a0.y);
        afA.u[1] = cvtpk(a0.z, a0.w);
        afA.u[2] = cvtpk(a1.x, a1.y);
        afA.u[3] = cvtpk(a1.z, a1.w);
        afB.u[0] = cvtpk(b0.x, b0.y);
        afB.u[1] = cvtpk(b0.z, b0.w);
        afB.u[2] = cvtpk(b1.x, b1.y);
        afB.u[3] = cvtpk(b1.z, b1.w);
        bf16x8 bws = *(const bf16x8*)(wrow + s * 32);
        accA = __builtin_amdgcn_mfma_f32_16x16x32_bf16(afA.v, bws, accA, 0, 0, 0);
        accB = __builtin_amdgcn_mfma_f32_16x16x32_bf16(afB.v, bws, accB, 0, 0, 0);
    }
#undef STAGE

    const int rowA = rowBase + wid * 32;
    const int rowB2 = rowA + 16;
#pragma unroll
    for (int r = 0; r < 4; ++r) {
        int oA = rowA + lk * 4 + r;
        int oB = rowB2 + lk * 4 + r;
        if (oA < N_NODES) h1b[(size_t)oA * HIDDEN + lm] = f2bf(accA[r]);
        if (oB < N_NODES) h1b[(size_t)oB * HIDDEN + lm] = f2bf(accB[r]);
    }
}

// ---------- tier-1 fused gemm || scatter ----------
// R26: gemm blocks FIRST (blockIdx < NGEMM). Blocks dispatch roughly in
// blockIdx order; the gemm is the long latency chain, so starting it at t=0
// (instead of after 512 scatter blocks) shortens the makespan. Scatter
// (latency-tolerant, LDS-atomic bound) fills the residual slots.

__global__ __launch_bounds__(256)
void k_buildA(const int* __restrict__ ei, const float* __restrict__ ew,
              int* __restrict__ bcursor, uint2* __restrict__ abuf,
              const float* __restrict__ x, const float* __restrict__ W1g,
              unsigned short* __restrict__ h1b) {
    __shared__ __align__(16) char smem[SM_SZ];
    int t = threadIdx.x;
    if (blockIdx.x >= NGEMM) {
        int* lh    = (int*)smem;                 // NBUK
        int* lbase = lh + NBUK;                  // NBUK
        int* lcur  = lbase + NBUK;               // NBUK
        int* sis64 = lcur + NBUK;                // 1
        if (t < 64) {
            int v = ei[2 * t + 1];
            unsigned long long bb = __ballot(v != 0);
            if (t == 0) sis64[0] = (bb == 0ULL) ? 1 : 0;
        }
        for (int i = t; i < NBUK; i += 256) { lh[i] = 0; lcur[i] = 0; }
        __syncthreads();
        int is64 = sis64[0];
        int s = (blockIdx.x - NGEMM) * TILE, e1 = min(s + TILE, N_EDGES);
        for (int e = s + t; e < e1; e += 256) {
            int c = eidx(ei, is64, N_EDGES + e);
            atomicAdd(&lh[c >> BSH], 1);
        }
        __syncthreads();
        for (int i = t; i < NBUK; i += 256)
            if (lh[i]) lbase[i] = atomicAdd(&bcursor[i], lh[i]);
        __syncthreads();
        for (int e = s + t; e < e1; e += 256) {
            int r = eidx(ei, is64, e);
            int c = eidx(ei, is64, N_EDGES + e);
            float w = ew[e];
            int b = c >> BSH;
            int off = lbase[b] + atomicAdd(&lcur[b], 1);
            if (off < CAP)
                abuf[((size_t)b << 13) + off] =
                    make_uint2((unsigned)r | ((unsigned)(c & (BNODES - 1)) << 17),
                               __float_as_uint(w));
        }
    } else {
        gemm_body(smem, blockIdx.x, t, x, W1g, h1b);
    }
}

// ---------- standalone MFMA gemm1 (tier-2) ----------

__global__ __launch_bounds__(256)
void k_gemm1(const float* __restrict__ x, const float* __restrict__ W1g,
             unsigned short* __restrict__ h1b) {
    __shared__ __align__(16) char smem[SM_SZ];
    gemm_body(smem, blockIdx.x, threadIdx.x, x, W1g, h1b);
}

// ---------- per-bucket counting sort, fixed-cap input ----------

__global__ __launch_bounds__(256)
void k_bsortF(const int* __restrict__ bcursor, const uint2* __restrict__ abuf,
              uint2* __restrict__ eperm, int* __restrict__ startA,
              int* __restrict__ cntA, float* __restrict__ dinv) {
    __shared__ uint2 se[BCAP];                     // 48 KB
    __shared__ int   cnt[BNODES];
    __shared__ int   scn[256];
    __shared__ int   cur[BNODES];
    __shared__ float wsum[BNODES];
    int t = threadIdx.x, b = blockIdx.x;
    int nb = min(bcursor[b], CAP);
    int base = b << 13;
    if (t < BNODES) { cnt[t] = 0; wsum[t] = 0.0f; }
    __syncthreads();

    bool fits = (nb <= BCAP);
    if (fits) {
        for (int k = t; k < nb; k += 256) {
            uint2 a = abuf[base + k];
            se[k] = a;
            int ln = (int)(a.x >> 17);
            atomicAdd(&cnt[ln], 1);
            atomicAdd(&wsum[ln], __uint_as_float(a.y));
        }
    } else {
        for (int k = t; k < nb; k += 256) {
            uint2 a = abuf[base + k];
            int ln = (int)(a.x >> 17);
            atomicAdd(&cnt[ln], 1);
            atomicAdd(&wsum[ln], __uint_as_float(a.y));
        }
    }
    __syncthreads();
    int v = (t < BNODES) ? cnt[t] : 0;
    scn[t] = v;
    __syncthreads();
    for (int off = 1; off < 256; off <<= 1) {
        int u = (t >= off) ? scn[t - off] : 0;
        __syncthreads();
        scn[t] += u;
        __syncthreads();
    }
    int excl = scn[t] - v;
    if (t < BNODES) {
        cur[t] = excl;
        int node = b * BNODES + t;
        if (node < N_NODES) {
            startA[node] = base + excl;
            cntA[node]   = cnt[t];
            dinv[node]   = rsqrtf(1.0f + wsum[t]);
        }
    }
    __syncthreads();
    if (fits) {
        for (int k = t; k < nb; k += 256) {
            uint2 a = se[k];
            int ln = (int)(a.x >> 17);
            int off = atomicAdd(&cur[ln], 1);
            eperm[base + off] = make_uint2(a.x & 0x1FFFFu, a.y);
        }
    } else {
        for (int k = t; k < nb; k += 256) {
            uint2 a = abuf[base + k];
            int ln = (int)(a.x >> 17);
            int off = atomicAdd(&cur[ln], 1);
            eperm[base + off] = make_uint2(a.x & 0x1FFFFu, a.y);
        }
    }
}

// ---------- tier-2 build kernels (contiguous layout, 52MB ws) ----------

__global__ __launch_bounds__(256)
void k_bhist(const int* __restrict__ ei, const int* __restrict__ flag,
             int* __restrict__ bcnt) {
    __shared__ int lh[NBUK];
    for (int i = threadIdx.x; i < NBUK; i += 256) lh[i] = 0;
    __syncthreads();
    int is64 = flag[0];
    int s = blockIdx.x * TILE, e1 = min(s + TILE, N_EDGES);
    for (int e = s + threadIdx.x; e < e1; e += 256) {
        int c = eidx(ei, is64, N_EDGES + e);
        atomicAdd(&lh[c >> BSH], 1);
    }
    __syncthreads();
    for (int i = threadIdx.x; i < NBUK; i += 256)
        if (lh[i]) atomicAdd(&bcnt[i], lh[i]);
}

__global__ void k_bscan(const int* __restrict__ bcnt, int* __restrict__ bstart,
                        int* __restrict__ bcursor) {
    __shared__ int s[1024];
    int t = threadIdx.x;
    int v = (t < NBUK) ? bcnt[t] : 0;
    s[t] = v;
    __syncthreads();
    for (int off = 1; off < 1024; off <<= 1) {
        int u = (t >= off) ? s[t - off] : 0;
        __syncthreads();
        s[t] += u;
        __syncthreads();
    }
    int excl = s[t] - v;
    if (t <= NBUK) bstart[t] = excl;
    if (t < NBUK)  bcursor[t] = excl;
}

__global__ __launch_bounds__(256)
void k_bscat(const int* __restrict__ ei, const float* __restrict__ ew,
             const int* __restrict__ flag, int* __restrict__ bcursor,
             uint2* __restrict__ abuf) {
    __shared__ int lh[NBUK];
    __shared__ int lbase[NBUK];
    __shared__ int lcur[NBUK];
    for (int i = threadIdx.x; i < NBUK; i += 256) { lh[i] = 0; lcur[i] = 0; }
    __syncthreads();
    int is64 = flag[0];
    int s = blockIdx.x * TILE, e1 = min(s + TILE, N_EDGES);
    for (int e = s + threadIdx.x; e < e1; e += 256) {
        int c = eidx(ei, is64, N_EDGES + e);
        atomicAdd(&lh[c >> BSH], 1);
    }
    __syncthreads();
    for (int i = threadIdx.x; i < NBUK; i += 256)
        if (lh[i]) lbase[i] = atomicAdd(&bcursor[i], lh[i]);
    __syncthreads();
    for (int e = s + threadIdx.x; e < e1; e += 256) {
        int r = eidx(ei, is64, e);
        int c = eidx(ei, is64, N_EDGES + e);
        float w = ew[e];
        int b = c >> BSH;
        int off = atomicAdd(&lcur[b], 1);
        abuf[lbase[b] + off] = make_uint2((unsigned)r | ((unsigned)(c & (BNODES - 1)) << 17),
                                          __float_as_uint(w));
    }
}

__global__ __launch_bounds__(256)
void k_bsortC(const int* __restrict__ bstart, const uint2* __restrict__ abuf,
              uint2* __restrict__ eperm, int* __restrict__ startA,
              int* __restrict__ cntA, float* __restrict__ dinv) {
    __shared__ uint2 se[BCAP];
    __shared__ int   cnt[BNODES];
    __shared__ int   scn[256];
    __shared__ int   cur[BNODES];
    __shared__ float wsum[BNODES];
    int t = threadIdx.x, b = blockIdx.x;
    int s0 = bstart[b], s1 = bstart[b + 1];
    int nb = s1 - s0;
    if (t < BNODES) { cnt[t] = 0; wsum[t] = 0.0f; }
    __syncthreads();
    bool fits = (nb <= BCAP);
    if (fits) {
        for (int k = t; k < nb; k += 256) {
            uint2 a = abuf[s0 + k];
            se[k] = a;
            int ln = (int)(a.x >> 17);
            atomicAdd(&cnt[ln], 1);
            atomicAdd(&wsum[ln], __uint_as_float(a.y));
        }
    } else {
        for (int k = t; k < nb; k += 256) {
            uint2 a = abuf[s0 + k];
            int ln = (int)(a.x >> 17);
            atomicAdd(&cnt[ln], 1);
            atomicAdd(&wsum[ln], __uint_as_float(a.y));
        }
    }
    __syncthreads();
    int v = (t < BNODES) ? cnt[t] : 0;
    scn[t] = v;
    __syncthreads();
    for (int off = 1; off < 256; off <<= 1) {
        int u = (t >= off) ? scn[t - off] : 0;
        __syncthreads();
        scn[t] += u;
        __syncthreads();
    }
    int excl = scn[t] - v;
    if (t < BNODES) {
        cur[t] = excl;
        int node = b * BNODES + t;
        if (node < N_NODES) {
            startA[node] = s0 + excl;
            cntA[node]   = cnt[t];
            dinv[node]   = rsqrtf(1.0f + wsum[t]);
        }
    }
    __syncthreads();
    if (fits) {
        for (int k = t; k < nb; k += 256) {
            uint2 a = se[k];
            int ln = (int)(a.x >> 17);
            int off = atomicAdd(&cur[ln], 1);
            eperm[s0 + off] = make_uint2(a.x & 0x1FFFFu, a.y);
        }
    } else {
        for (int k = t; k < nb; k += 256) {
            uint2 a = abuf[s0 + k];
            int ln = (int)(a.x >> 17);
            int off = atomicAdd(&cur[ln], 1);
            eperm[s0 + off] = make_uint2(a.x & 0x1FFFFu, a.y);
        }
    }
}

// ---------- gather layer 1 (+ bias + self-loop) fused with gemm2 ----------

__global__ __launch_bounds__(256)
void k_gather1(const int* __restrict__ startA, const int* __restrict__ cntA,
               const uint2* __restrict__ ep, const float* __restrict__ dinv,
               const unsigned short* __restrict__ h1b, const float* __restrict__ b1,
               const float* __restrict__ W2g, float* __restrict__ x1,
               unsigned short* __restrict__ h2b) {
    __shared__ float sW2[HIDDEN * NCLS];
    __shared__ float sv[16][HIDDEN + 1];
    int t = threadIdx.x;
    if (t < HIDDEN * NCLS) sW2[t] = W2g[t];
    int ln = t >> 4, es = (t >> 2) & 3, fs = t & 3;
    int i = blockIdx.x * 16 + ln;
    bool act = (i < N_NODES);
    float4 a = make_float4(0.0f, 0.0f, 0.0f, 0.0f);
    float4 b = make_float4(0.0f, 0.0f, 0.0f, 0.0f);
    if (act) {
        int s0 = startA[i], n = cntA[i];
        int k = es;
        for (; k + 4 < n; k += 8) {
            uint2 e0 = ep[s0 + k];
            uint2 e1 = ep[s0 + k + 4];
            int r0 = (int)e0.x, r1 = (int)e1.x;
            float w0 = __uint_as_float(e0.y) * dinv[r0];
            float w1 = __uint_as_float(e1.y) * dinv[r1];
            uint2 p0 = *(const uint2*)(h1b + ((size_t)r0 << 4) + 4 * fs);
            uint2 p1 = *(const uint2*)(h1b + ((size_t)r1 << 4) + 4 * fs);
            a.x = fmaf(w0, __uint_as_float(p0.x << 16),          a.x);
            a.y = fmaf(w0, __uint_as_float(p0.x & 0xFFFF0000u),  a.y);
            a.z = fmaf(w0, __uint_as_float(p0.y << 16),          a.z);
            a.w = fmaf(w0, __uint_as_float(p0.y & 0xFFFF0000u),  a.w);
            b.x = fmaf(w1, __uint_as_float(p1.x << 16),          b.x);
            b.y = fmaf(w1, __uint_as_float(p1.x & 0xFFFF0000u),  b.y);
            b.z = fmaf(w1, __uint_as_float(p1.y << 16),          b.z);
            b.w = fmaf(w1, __uint_as_float(p1.y & 0xFFFF0000u),  b.w);
        }
        if (k < n) {
            uint2 e0 = ep[s0 + k];
            int r0 = (int)e0.x;
            float w0 = __uint_as_float(e0.y) * dinv[r0];
            uint2 p0 = *(const uint2*)(h1b + ((size_t)r0 << 4) + 4 * fs);
            a.x = fmaf(w0, __uint_as_float(p0.x << 16),          a.x);
            a.y = fmaf(w0, __uint_as_float(p0.x & 0xFFFF0000u),  a.y);
            a.z = fmaf(w0, __uint_as_float(p0.y << 16),          a.z);
            a.w = fmaf(w0, __uint_as_float(p0.y & 0xFFFF0000u),  a.w);
        }
    }
    a.x += b.x; a.y += b.y; a.z += b.z; a.w += b.w;
    a.x += __shfl_xor(a.x, 4); a.y += __shfl_xor(a.y, 4);
    a.z += __shfl_xor(a.z, 4); a.w += __shfl_xor(a.w, 4);
    a.x += __shfl_xor(a.x, 8); a.y += __shfl_xor(a.y, 8);
    a.z += __shfl_xor(a.z, 8); a.w += __shfl_xor(a.w, 8);
    if (act && es == 0) {
        float di = dinv[i], d2 = di * di;
        uint2 ps = *(const uint2*)(h1b + ((size_t)i << 4) + 4 * fs);
        const float* b1r = b1 + 4 * fs;
        float v0 = di * a.x + d2 * __uint_as_float(ps.x << 16)         + b1r[0];
        float v1 = di * a.y + d2 * __uint_as_float(ps.x & 0xFFFF0000u) + b1r[1];
        float v2 = di * a.z + d2 * __uint_as_float(ps.y << 16)         + b1r[2];
        float v3 = di * a.w + d2 * __uint_as_float(ps.y & 0xFFFF0000u) + b1r[3];
        *(float4*)(x1 + (size_t)i * HIDDEN + 4 * fs) = make_float4(v0, v1, v2, v3);
        sv[ln][4 * fs + 0] = v0; sv[ln][4 * fs + 1] = v1;
        sv[ln][4 * fs + 2] = v2; sv[ln][4 * fs + 3] = v3;
    }
    __syncthreads();
    int j = t & 15;
    if (act && j < 8) {
        float acc2 = 0.0f;
        if (j < NCLS) {
#pragma unroll
            for (int kk = 0; kk < HIDDEN; ++kk)
                acc2 = fmaf(sv[ln][kk], sW2[kk * NCLS + j], acc2);
        }
        h2b[(size_t)i * 8 + j] = (j < NCLS) ? f2bf(acc2) : (unsigned short)0;
    }
}

// ---------- gather layer 2 fused with log_softmax ----------

__global__ __launch_bounds__(256)
void k_gather2(const int* __restrict__ startA, const int* __restrict__ cntA,
               const uint2* __restrict__ ep, const float* __restrict__ dinv,
               const unsigned short* __restrict__ h2b, const float* __restrict__ b2,
               float* __restrict__ out) {
    __shared__ float sv[16][9];
    int t = threadIdx.x;
    int ln = t >> 4, es = (t >> 1) & 7, fs = t & 1;
    int i = blockIdx.x * 16 + ln;
    bool act = (i < N_NODES);
    float4 a = make_float4(0.0f, 0.0f, 0.0f, 0.0f);
    float4 b = make_float4(0.0f, 0.0f, 0.0f, 0.0f);
    if (act) {
        int s0 = startA[i], n = cntA[i];
        int k = es;
        for (; k + 8 < n; k += 16) {
            uint2 e0 = ep[s0 + k];
            uint2 e1 = ep[s0 + k + 8];
            int r0 = (int)e0.x, r1 = (int)e1.x;
            float w0 = __uint_as_float(e0.y) * dinv[r0];
            float w1 = __uint_as_float(e1.y) * dinv[r1];
            uint2 p0 = *(const uint2*)(h2b + ((size_t)r0 << 3) + 4 * fs);
            uint2 p1 = *(const uint2*)(h2b + ((size_t)r1 << 3) + 4 * fs);
            a.x = fmaf(w0, __uint_as_float(p0.x << 16),          a.x);
            a.y = fmaf(w0, __uint_as_float(p0.x & 0xFFFF0000u),  a.y);
            a.z = fmaf(w0, __uint_as_float(p0.y << 16),          a.z);
            a.w = fmaf(w0, __uint_as_float(p0.y & 0xFFFF0000u),  a.w);
            b.x = fmaf(w1, __uint_as_float(p1.x << 16),          b.x);
            b.y = fmaf(w1, __uint_as_float(p1.x & 0xFFFF0000u),  b.y);
            b.z = fmaf(w1, __uint_as_float(p1.y << 16),          b.z);
            b.w = fmaf(w1, __uint_as_float(p1.y & 0xFFFF0000u),  b.w);
        }
        if (k < n) {
            uint2 e0 = ep[s0 + k];
            int r0 = (int)e0.x;
            float w0 = __uint_as_float(e0.y) * dinv[r0];
            uint2 p0 = *(const uint2*)(h2b + ((size_t)r0 << 3) + 4 * fs);
            a.x = fmaf(w0, __uint_as_float(p0.x << 16),          a.x);
            a.y = fmaf(w0, __uint_as_float(p0.x & 0xFFFF0000u),  a.y);
            a.z = fmaf(w0, __uint_as_float(p0.y << 16),          a.z);
            a.w = fmaf(w0, __uint_as_float(p0.y & 0xFFFF0000u),  a.w);
        }
    }
    a.x += b.x; a.y += b.y; a.z += b.z; a.w += b.w;
    a.x += __shfl_xor(a.x, 2); a.y += __shfl_xor(a.y, 2);
    a.z += __shfl_xor(a.z, 2); a.w += __shfl_xor(a.w, 2);
    a.x += __shfl_xor(a.x, 4); a.y += __shfl_xor(a.y, 4);
    a.z += __shfl_xor(a.z, 4); a.w += __shfl_xor(a.w, 4);
    a.x += __shfl_xor(a.x, 8); a.y += __shfl_xor(a.y, 8);
    a.z += __shfl_xor(a.z, 8); a.w += __shfl_xor(a.w, 8);
    if (act && es == 0) {
        float di = dinv[i], d2 = di * di;
        uint2 ps = *(const uint2*)(h2b + ((size_t)i << 3) + 4 * fs);
        int c0 = 4 * fs;
        float s0v = __uint_as_float(ps.x << 16);
        float s1v = __uint_as_float(ps.x & 0xFFFF0000u);
        float s2v = __uint_as_float(ps.y << 16);
        float s3v = __uint_as_float(ps.y & 0xFFFF0000u);
        float v0 = di * a.x + d2 * s0v + ((c0 + 0) < NCLS ? b2[c0 + 0] : 0.0f);
        float v1 = di * a.y + d2 * s1v + ((c0 + 1) < NCLS ? b2[c0 + 1] : 0.0f);
        float v2 = di * a.z + d2 * s2v + ((c0 + 2) < NCLS ? b2[c0 + 2] : 0.0f);
        float v3 = di * a.w + d2 * s3v + ((c0 + 3) < NCLS ? b2[c0 + 3] : 0.0f);
        sv[ln][c0 + 0] = v0; sv[ln][c0 + 1] = v1;
        sv[ln][c0 + 2] = v2; sv[ln][c0 + 3] = v3;
    }
    __syncthreads();
    int j = t & 15;
    if (act && j < NCLS) {
        float m = -1e30f;
#pragma unroll
        for (int c = 0; c < NCLS; ++c) m = fmaxf(m, sv[ln][c]);
        float ssum = 0.0f;
#pragma unroll
        for (int c = 0; c < NCLS; ++c) ssum += __expf(sv[ln][c] - m);
        out[(size_t)i * NCLS + j] = sv[ln][j] - m - __logf(ssum);
    }
}

// ---------- tier-3 atomic fallback kernels (small ws) ----------

__global__ void k_initdeg(float* __restrict__ deg) {
    int i = blockIdx.x * 256 + threadIdx.x;
    if (i < N_NODES) deg[i] = 1.0f;
}

__global__ void k_degacc(const int* __restrict__ ei, const float* __restrict__ w,
                         const int* __restrict__ flag, float* __restrict__ deg) {
    int e = blockIdx.x * 256 + threadIdx.x;
    if (e >= N_EDGES) return;
    int c = eidx(ei, flag[0], N_EDGES + e);
    atomicAdd(&deg[c], w[e]);
}

__global__ void k_dinv(float* __restrict__ deg) {
    int i = blockIdx.x * 256 + threadIdx.x;
    if (i < N_NODES) {
        float d = deg[i];
        deg[i] = (d > 0.0f) ? rsqrtf(d) : 0.0f;
    }
}

__global__ __launch_bounds__(256)
void k_gemm1f(const float* __restrict__ x, const float* __restrict__ W1g,
              float* __restrict__ h1) {
    __shared__ float w1s[D_FEAT * HIDDEN];
    for (int p = threadIdx.x; p < D_FEAT * HIDDEN; p += 256) w1s[p] = W1g[p];
    __syncthreads();
    const int total = N_NODES * HIDDEN;
    for (int t = blockIdx.x * 256 + threadIdx.x; t < total; t += gridDim.x * 256) {
        int i = t >> 4, j = t & 15;
        const float4* xr = (const float4*)(x + (size_t)i * D_FEAT);
        float acc = 0.0f;
#pragma unroll 4
        for (int k4 = 0; k4 < D_FEAT / 4; ++k4) {
            float4 xv = xr[k4];
            int kb = (k4 << 6) + j;
            acc = fmaf(xv.x, w1s[kb],      acc);
            acc = fmaf(xv.y, w1s[kb + 16], acc);
            acc = fmaf(xv.z, w1s[kb + 32], acc);
            acc = fmaf(xv.w, w1s[kb + 48], acc);
        }
        h1[t] = acc;
    }
}

__global__ __launch_bounds__(256)
void k_scatter1(const int* __restrict__ ei, const float* __restrict__ w,
                const int* __restrict__ flag, const float* __restrict__ dinv,
                const float* __restrict__ h1, float* __restrict__ agg1) {
    int t = blockIdx.x * 256 + threadIdx.x;
    if (t >= N_EDGES * HIDDEN) return;
    int e = t >> 4, j = t & 15;
    int is64 = flag[0];
    int r = eidx(ei, is64, e);
    int c = eidx(ei, is64, N_EDGES + e);
    float nrm = dinv[r] * w[e] * dinv[c];
    atomicAdd(&agg1[(size_t)c * HIDDEN + j], nrm * h1[(size_t)r * HIDDEN + j]);
}

__global__ void k_fin1_gemm2(const float* __restrict__ b1, const float* __restrict__ W2,
                             const float* __restrict__ dinv, const float* __restrict__ h1,
                             float* __restrict__ x1, float* __restrict__ h2) {
    int i = blockIdx.x * 256 + threadIdx.x;
    if (i >= N_NODES) return;
    float d2 = dinv[i] * dinv[i];
    float v[HIDDEN];
#pragma unroll
    for (int k = 0; k < HIDDEN; ++k)
        v[k] = x1[(size_t)i * HIDDEN + k] + d2 * h1[(size_t)i * HIDDEN + k] + b1[k];
#pragma unroll
    for (int k = 0; k < HIDDEN; ++k)
        x1[(size_t)i * HIDDEN + k] = v[k];
#pragma unroll
    for (int j = 0; j < NCLS; ++j) {
        float a = 0.0f;
#pragma unroll
        for (int k = 0; k < HIDDEN; ++k) a = fmaf(v[k], W2[k * NCLS + j], a);
        h2[(size_t)i * NCLS + j] = a;
    }
}

__global__ __launch_bounds__(256)
void k_scatter2(const int* __restrict__ ei, const float* __restrict__ w,
                const int* __restrict__ flag, const float* __restrict__ dinv,
                const float* __restrict__ h2, float* __restrict__ agg2) {
    int t = blockIdx.x * 256 + threadIdx.x;
    if (t >= N_EDGES * NCLS) return;
    int e = t / NCLS, j = t - e * NCLS;
    int is64 = flag[0];
    int r = eidx(ei, is64, e);
    int c = eidx(ei, is64, N_EDGES + e);
    float nrm = dinv[r] * w[e] * dinv[c];
    atomicAdd(&agg2[(size_t)c * NCLS + j], nrm * h2[(size_t)r * NCLS + j]);
}

__global__ void k_final(const float* __restrict__ agg2, const float* __restrict__ h2,
                        const float* __restrict__ dinv, const float* __restrict__ b2,
                        float* __restrict__ out) {
    int i = blockIdx.x * 256 + threadIdx.x;
    if (i >= N_NODES) return;
    float d2 = dinv[i] * dinv[i];
    float v[NCLS];
    float m = -1e30f;
#pragma unroll
    for (int j = 0; j < NCLS; ++j) {
        v[j] = agg2[(size_t)i * NCLS + j] + d2 * h2[(size_t)i * NCLS + j] + b2[j];
        m = fmaxf(m, v[j]);
    }
    float s = 0.0f;
#pragma unroll
    for (int j = 0; j < NCLS; ++j) s += __expf(v[j] - m);
    float l = __logf(s);
#pragma unroll
    for (int j = 0; j < NCLS; ++j) out[(size_t)i * NCLS + j] = v[j] - m - l;
}

// ---------- launch ----------

extern "C" void kernel_launch(void* const* d_in, const int* in_sizes, int n_in,
                              void* d_out, int out_size, void* d_ws, size_t ws_size,
                              hipStream_t stream) {
    const float* x  = (const float*)d_in[0];
    const float* W1 = (const float*)d_in[1];
    const float* b1 = (const float*)d_in[2];
    const float* W2 = (const float*)d_in[3];
    const float* b2 = (const float*)d_in[4];
    const float* ew = (const float*)d_in[5];
    const int*   ei = (const int*)d_in[6];

    float* out = (float*)d_out;
    float* lsm = out;                               // [N, 6]
    float* x1  = out + (size_t)N_NODES * NCLS;      // [N, 16]

    const int NB_N = (N_NODES + 255) / 256;
    const int NB_E = (N_EDGES + 255) / 256;

    float* W    = (float*)d_ws;
    int*   flag = (int*)d_ws;

    // ---- tier-1 layout (4B words), fixed-cap buckets ----
    int*   bcursor1 = (int*)(W + 0);          // 782
    int*   startA1  = (int*)(W + 1024);       // 100000
    int*   cntA1    = (int*)(W + 101024);     // 100000
    float* dinv1    = W + 201024;             // 100000
    unsigned short* h1b1 = (unsigned short*)(W + 301056);  // 800000 words
    unsigned short* h2b1 = (unsigned short*)(W + 1101056); // 400000 words
    uint2* abuf1    = (uint2*)(W + 1501056);  // 782*8192 uint2 = 12812288 words
    uint2* eperm1   = (uint2*)(W + 14313344); // 12812288 words -> ends 27125632
    const size_t NEED1 = (size_t)27125632 * 4;      // ~108.5 MB

    // ---- tier-2 layout (contiguous, ~52.4 MB) ----
    int*   bcnt2    = (int*)(W + 256);
    int*   bstart2  = (int*)(W + 1152);
    int*   bcursor2 = (int*)(W + 2048);
    int*   startA2  = (int*)(W + 2944);       // 100001
    float* dinv2    = W + 102948;
    uint2* abuf2    = (uint2*)(W + 202948);   // aliased with h1b2/h2b2 after bsort
    unsigned short* h1b2 = (unsigned short*)(W + 202948);
    unsigned short* h2b2 = (unsigned short*)(W + 1802948);
    uint2* eperm2   = (uint2*)(W + 6602948);
    int*   cntA2    = (int*)(W + 13002948);   // 100000 -> ends 13102948
    const size_t NEED2 = (size_t)13102948 * 4;      // ~52.4 MB

    if (ws_size >= NEED1) {
        hipMemsetAsync(bcursor1, 0, NBUK * 4, stream);
        k_buildA<<<NGEMM + NBLK_A, 256, 0, stream>>>(ei, ew, bcursor1, abuf1,
                                                     x, W1, h1b1);
        k_bsortF<<<NBUK, 256, 0, stream>>>(bcursor1, abuf1, eperm1,
                                           startA1, cntA1, dinv1);
        k_gather1<<<(N_NODES + 15) / 16, 256, 0, stream>>>(startA1, cntA1, eperm1,
                                                           dinv1, h1b1, b1, W2,
                                                           x1, h2b1);
        k_gather2<<<(N_NODES + 15) / 16, 256, 0, stream>>>(startA1, cntA1, eperm1,
                                                           dinv1, h2b1, b2, lsm);
    } else if (ws_size >= NEED2) {
        hipMemsetAsync(bcnt2, 0, (NBUK + 1) * 4, stream);
        k_detect<<<1, 64, 0, stream>>>(ei, flag);
        k_bhist <<<NBLK_A, 256, 0, stream>>>(ei, flag, bcnt2);
        k_bscan <<<1, 1024, 0, stream>>>(bcnt2, bstart2, bcursor2);
        k_bscat <<<NBLK_A, 256, 0, stream>>>(ei, ew, flag, bcursor2, abuf2);
        k_bsortC<<<NBUK, 256, 0, stream>>>(bstart2, abuf2, eperm2,
                                           startA2, cntA2, dinv2);
        k_gemm1 <<<NGEMM, 256, 0, stream>>>(x, W1, h1b2);
        k_gather1<<<(N_NODES + 15) / 16, 256, 0, stream>>>(startA2, cntA2, eperm2,
                                                           dinv2, h1b2, b1, W2,
                                                           x1, h2b2);
        k_gather2<<<(N_NODES + 15) / 16, 256, 0, stream>>>(startA2, cntA2, eperm2,
                                                           dinv2, h2b2, b2, lsm);
    } else {
        float* deg  = W + 1024;
        float* fh1  = W + 101376;
        float* fh2  = fh1 + (size_t)N_NODES * HIDDEN;
        float* agg2 = fh2 + (size_t)N_NODES * NCLS;
        hipMemsetAsync(x1,   0, (size_t)N_NODES * HIDDEN * sizeof(float), stream);
        hipMemsetAsync(agg2, 0, (size_t)N_NODES * NCLS   * sizeof(float), stream);
        k_detect <<<1, 64, 0, stream>>>(ei, flag);
        k_initdeg<<<NB_N, 256, 0, stream>>>(deg);
        k_degacc <<<NB_E, 256, 0, stream>>>(ei, ew, flag, deg);
        k_dinv   <<<NB_N, 256, 0, stream>>>(deg);
        k_gemm1f <<<2048, 256, 0, stream>>>(x, W1, fh1);
        k_scatter1<<<(N_EDGES * HIDDEN + 255) / 256, 256, 0, stream>>>(ei, ew, flag, deg, fh1, x1);
        k_fin1_gemm2<<<NB_N, 256, 0, stream>>>(b1, W2, deg, fh1, x1, fh2);
        k_scatter2<<<(N_EDGES * NCLS + 255) / 256, 256, 0, stream>>>(ei, ew, flag, deg, fh2, agg2);
        k_final  <<<NB_N, 256, 0, stream>>>(agg2, fh2, deg, b2, lsm);
    }
}

// Round 27
// 227.884 us; speedup vs baseline: 1.0673x; 1.0673x over previous
//
#include <hip/hip_runtime.h>

#define N_NODES 100000
#define N_EDGES 3200000
#define D_FEAT  512
#define HIDDEN  16
#define NCLS    6
#define BSH     7                      // bucket = col >> 7
#define BNODES  128                    // nodes per bucket
#define NBUK    782                    // ceil(N_NODES/128)
#define BCAP    6144                   // LDS staging capacity in bsort
#define CAP     8192                   // fixed bucket capacity (mean 4092 + 64 sigma)
#define NBLK_A  512                    // scatter blocks: exactly 2 per CU
#define TILE    6250                   // ceil(N_EDGES/NBLK_A)
#define NGEMM   782                    // gemm tile blocks (128 rows each)
#define W1LD    522                    // W1T row stride in bf16 (512+10 -> 16 distinct bank starts)

// gemm smem layout (bytes): w1t[16*522]u16 = 16704 | xb0 16384 | xb1 16384
#define SM_W1   0
#define SM_XB0  16704
#define SM_XB1  33088
#define SM_SZ   49472

typedef __attribute__((ext_vector_type(8))) short bf16x8;
typedef __attribute__((ext_vector_type(4))) float f32x4;
typedef __attribute__((address_space(1))) const float gfloat;
typedef __attribute__((address_space(3))) float lfloat;

// ---------- helpers ----------

__device__ __forceinline__ int eidx(const int* __restrict__ ei, int is64, int pos) {
    return is64 ? ei[2 * (long long)pos] : ei[pos];
}

__global__ void k_detect(const int* __restrict__ ei, int* __restrict__ flag) {
    int v = ei[2 * threadIdx.x + 1];
    unsigned long long b = __ballot(v != 0);
    if (threadIdx.x == 0) flag[0] = (b == 0ULL) ? 1 : 0;
}

__device__ __forceinline__ unsigned short f2bf(float f) {     // RNE f32->bf16
    unsigned u = __float_as_uint(f);
    return (unsigned short)((u + 0x7FFFu + ((u >> 16) & 1u)) >> 16);
}

__device__ __forceinline__ unsigned cvtpk(float lo, float hi) {
    unsigned r;
    asm volatile("v_cvt_pk_bf16_f32 %0, %1, %2" : "=v"(r) : "v"(lo), "v"(hi));
    return r;
}

union bfrag {
    unsigned u[4];
    bf16x8   v;
};

// gemm body (R24 zero-VGPR staging + R25 both-sides XOR swizzle + R26 W1LD).
// Session post-mortem: buildA is latency/schedule bound (barrier drain +
// mixed-branch allocation); R22-R26 counter-verified levers all <=2%.
// R26 lesson: scatter blocks must dispatch FIRST -- heterogeneous residency
// (scatter+gemm on each CU) hides the gemm's latency; all-gemm-first
// regressed 230->243.
__device__ __forceinline__ void gemm_body(char* smem, int bid, int t,
                                          const float* __restrict__ x,
                                          const float* __restrict__ W1g,
                                          unsigned short* __restrict__ h1b) {
    unsigned short* w1t = (unsigned short*)(smem + SM_W1);
    float* xb0 = (float*)(smem + SM_XB0);
    float* xb1 = (float*)(smem + SM_XB1);
    const int wid = t >> 6;
    const int L   = t & 63;
    const int lm  = L & 15;
    const int lk  = L >> 4;
    const int rowBase = bid * 128;

    for (int p = t; p < D_FEAT * HIDDEN; p += 256) {
        int k = p >> 4, j = p & 15;             // W1[k][j], coalesced read
        w1t[j * W1LD + k] = f2bf(W1g[p]);
    }

    // async stage of chunk s into buf: linear LDS dest (slot f = row*8+c),
    // global source PRE-SWIZZLED: slot (row,c) <- global quad c^(row&7).
#define STAGE(buf, s)                                                        \
    {                                                                        \
        _Pragma("unroll")                                                    \
        for (int it = 0; it < 4; ++it) {                                     \
            int f = it * 256 + t;                                            \
            int row = f >> 3, c = f & 7;                                     \
            int cs = c ^ (row & 7);                                          \
            int grow = min(rowBase + row, N_NODES - 1);                      \
            const float* gp = x + (size_t)grow * D_FEAT + (s) * 32 + cs * 4; \
            float* lp = (buf) + (size_t)(it * 256 + wid * 64) * 4;           \
            __builtin_amdgcn_global_load_lds((gfloat*)gp, (lfloat*)lp,       \
                                             16, 0, 0);                      \
        }                                                                    \
    }

    STAGE(xb0, 0);

    f32x4 accA = {0.0f, 0.0f, 0.0f, 0.0f};
    f32x4 accB = {0.0f, 0.0f, 0.0f, 0.0f};
    const int rA = wid * 32 + lm;              // lds row, tile A
    const int rB = rA + 16;                    // lds row, tile B
    const int qA0 = (lk * 2) ^ (rA & 7), qA1 = (lk * 2 + 1) ^ (rA & 7);
    const int qB0 = (lk * 2) ^ (rB & 7), qB1 = (lk * 2 + 1) ^ (rB & 7);
    const unsigned short* wrow = w1t + lm * W1LD + lk * 8;

#pragma unroll
    for (int s = 0; s < 16; ++s) {
        float* bcur = (s & 1) ? xb1 : xb0;     // compile-time (full unroll)
        float* bnxt = (s & 1) ? xb0 : xb1;
        __syncthreads();                       // drains vmcnt: bcur staged
        if (s < 15) STAGE(bnxt, s + 1);
        float4 a0 = *(const float4*)(bcur + rA * 32 + qA0 * 4);
        float4 a1 = *(const float4*)(bcur + rA * 32 + qA1 * 4);
        float4 b0 = *(const float4*)(bcur + rB * 32 + qB0 * 4);
        float4 b1 = *(const float4*)(bcur + rB * 32 + qB1 * 4);
        bfrag afA, afB;
        afA.u[0] = cvtpk(a0.x, a0.y);
        afA.u[1] = cvtpk(a0.z, a0.w);
        afA.u[2] = cvtpk(a1.x, a1.y);
        afA.u[3] = cvtpk(a1.z, a1.w);
        afB.u[0] = cvtpk(b0.x, b0.y);
        afB.u[1] = cvtpk(b0.z, b0.w);
        afB.u[2] = cvtpk(b1.x, b1.y);
        afB.u[3] = cvtpk(b1.z, b1.w);
        bf16x8 bws = *(const bf16x8*)(wrow + s * 32);
        accA = __builtin_amdgcn_mfma_f32_16x16x32_bf16(afA.v, bws, accA, 0, 0, 0);
        accB = __builtin_amdgcn_mfma_f32_16x16x32_bf16(afB.v, bws, accB, 0, 0, 0);
    }
#undef STAGE

    const int rowA = rowBase + wid * 32;
    const int rowB2 = rowA + 16;
#pragma unroll
    for (int r = 0; r < 4; ++r) {
        int oA = rowA + lk * 4 + r;
        int oB = rowB2 + lk * 4 + r;
        if (oA < N_NODES) h1b[(size_t)oA * HIDDEN + lm] = f2bf(accA[r]);
        if (oB < N_NODES) h1b[(size_t)oB * HIDDEN + lm] = f2bf(accB[r]);
    }
}

// ---------- tier-1 fused scatter || gemm (scatter blocks FIRST) ----------

__global__ __launch_bounds__(256)
void k_buildA(const int* __restrict__ ei, const float* __restrict__ ew,
              int* __restrict__ bcursor, uint2* __restrict__ abuf,
              const float* __restrict__ x, const float* __restrict__ W1g,
              unsigned short* __restrict__ h1b) {
    __shared__ __align__(16) char smem[SM_SZ];
    int t = threadIdx.x;
    if (blockIdx.x < NBLK_A) {
        int* lh    = (int*)smem;                 // NBUK
        int* lbase = lh + NBUK;                  // NBUK
        int* lcur  = lbase + NBUK;               // NBUK
        int* sis64 = lcur + NBUK;                // 1
        if (t < 64) {
            int v = ei[2 * t + 1];
            unsigned long long bb = __ballot(v != 0);
            if (t == 0) sis64[0] = (bb == 0ULL) ? 1 : 0;
        }
        for (int i = t; i < NBUK; i += 256) { lh[i] = 0; lcur[i] = 0; }
        __syncthreads();
        int is64 = sis64[0];
        int s = blockIdx.x * TILE, e1 = min(s + TILE, N_EDGES);
        for (int e = s + t; e < e1; e += 256) {
            int c = eidx(ei, is64, N_EDGES + e);
            atomicAdd(&lh[c >> BSH], 1);
        }
        __syncthreads();
        for (int i = t; i < NBUK; i += 256)
            if (lh[i]) lbase[i] = atomicAdd(&bcursor[i], lh[i]);
        __syncthreads();
        for (int e = s + t; e < e1; e += 256) {
            int r = eidx(ei, is64, e);
            int c = eidx(ei, is64, N_EDGES + e);
            float w = ew[e];
            int b = c >> BSH;
            int off = lbase[b] + atomicAdd(&lcur[b], 1);
            if (off < CAP)
                abuf[((size_t)b << 13) + off] =
                    make_uint2((unsigned)r | ((unsigned)(c & (BNODES - 1)) << 17),
                               __float_as_uint(w));
        }
    } else {
        gemm_body(smem, blockIdx.x - NBLK_A, t, x, W1g, h1b);
    }
}

// ---------- standalone MFMA gemm1 (tier-2) ----------

__global__ __launch_bounds__(256)
void k_gemm1(const float* __restrict__ x, const float* __restrict__ W1g,
             unsigned short* __restrict__ h1b) {
    __shared__ __align__(16) char smem[SM_SZ];
    gemm_body(smem, blockIdx.x, threadIdx.x, x, W1g, h1b);
}

// ---------- per-bucket counting sort, fixed-cap input ----------

__global__ __launch_bounds__(256)
void k_bsortF(const int* __restrict__ bcursor, const uint2* __restrict__ abuf,
              uint2* __restrict__ eperm, int* __restrict__ startA,
              int* __restrict__ cntA, float* __restrict__ dinv) {
    __shared__ uint2 se[BCAP];                     // 48 KB
    __shared__ int   cnt[BNODES];
    __shared__ int   scn[256];
    __shared__ int   cur[BNODES];
    __shared__ float wsum[BNODES];
    int t = threadIdx.x, b = blockIdx.x;
    int nb = min(bcursor[b], CAP);
    int base = b << 13;
    if (t < BNODES) { cnt[t] = 0; wsum[t] = 0.0f; }
    __syncthreads();

    bool fits = (nb <= BCAP);
    if (fits) {
        for (int k = t; k < nb; k += 256) {
            uint2 a = abuf[base + k];
            se[k] = a;
            int ln = (int)(a.x >> 17);
            atomicAdd(&cnt[ln], 1);
            atomicAdd(&wsum[ln], __uint_as_float(a.y));
        }
    } else {
        for (int k = t; k < nb; k += 256) {
            uint2 a = abuf[base + k];
            int ln = (int)(a.x >> 17);
            atomicAdd(&cnt[ln], 1);
            atomicAdd(&wsum[ln], __uint_as_float(a.y));
        }
    }
    __syncthreads();
    int v = (t < BNODES) ? cnt[t] : 0;
    scn[t] = v;
    __syncthreads();
    for (int off = 1; off < 256; off <<= 1) {
        int u = (t >= off) ? scn[t - off] : 0;
        __syncthreads();
        scn[t] += u;
        __syncthreads();
    }
    int excl = scn[t] - v;
    if (t < BNODES) {
        cur[t] = excl;
        int node = b * BNODES + t;
        if (node < N_NODES) {
            startA[node] = base + excl;
            cntA[node]   = cnt[t];
            dinv[node]   = rsqrtf(1.0f + wsum[t]);
        }
    }
    __syncthreads();
    if (fits) {
        for (int k = t; k < nb; k += 256) {
            uint2 a = se[k];
            int ln = (int)(a.x >> 17);
            int off = atomicAdd(&cur[ln], 1);
            eperm[base + off] = make_uint2(a.x & 0x1FFFFu, a.y);
        }
    } else {
        for (int k = t; k < nb; k += 256) {
            uint2 a = abuf[base + k];
            int ln = (int)(a.x >> 17);
            int off = atomicAdd(&cur[ln], 1);
            eperm[base + off] = make_uint2(a.x & 0x1FFFFu, a.y);
        }
    }
}

// ---------- tier-2 build kernels (contiguous layout, 52MB ws) ----------

__global__ __launch_bounds__(256)
void k_bhist(const int* __restrict__ ei, const int* __restrict__ flag,
             int* __restrict__ bcnt) {
    __shared__ int lh[NBUK];
    for (int i = threadIdx.x; i < NBUK; i += 256) lh[i] = 0;
    __syncthreads();
    int is64 = flag[0];
    int s = blockIdx.x * TILE, e1 = min(s + TILE, N_EDGES);
    for (int e = s + threadIdx.x; e < e1; e += 256) {
        int c = eidx(ei, is64, N_EDGES + e);
        atomicAdd(&lh[c >> BSH], 1);
    }
    __syncthreads();
    for (int i = threadIdx.x; i < NBUK; i += 256)
        if (lh[i]) atomicAdd(&bcnt[i], lh[i]);
}

__global__ void k_bscan(const int* __restrict__ bcnt, int* __restrict__ bstart,
                        int* __restrict__ bcursor) {
    __shared__ int s[1024];
    int t = threadIdx.x;
    int v = (t < NBUK) ? bcnt[t] : 0;
    s[t] = v;
    __syncthreads();
    for (int off = 1; off < 1024; off <<= 1) {
        int u = (t >= off) ? s[t - off] : 0;
        __syncthreads();
        s[t] += u;
        __syncthreads();
    }
    int excl = s[t] - v;
    if (t <= NBUK) bstart[t] = excl;
    if (t < NBUK)  bcursor[t] = excl;
}

__global__ __launch_bounds__(256)
void k_bscat(const int* __restrict__ ei, const float* __restrict__ ew,
             const int* __restrict__ flag, int* __restrict__ bcursor,
             uint2* __restrict__ abuf) {
    __shared__ int lh[NBUK];
    __shared__ int lbase[NBUK];
    __shared__ int lcur[NBUK];
    for (int i = threadIdx.x; i < NBUK; i += 256) { lh[i] = 0; lcur[i] = 0; }
    __syncthreads();
    int is64 = flag[0];
    int s = blockIdx.x * TILE, e1 = min(s + TILE, N_EDGES);
    for (int e = s + threadIdx.x; e < e1; e += 256) {
        int c = eidx(ei, is64, N_EDGES + e);
        atomicAdd(&lh[c >> BSH], 1);
    }
    __syncthreads();
    for (int i = threadIdx.x; i < NBUK; i += 256)
        if (lh[i]) lbase[i] = atomicAdd(&bcursor[i], lh[i]);
    __syncthreads();
    for (int e = s + threadIdx.x; e < e1; e += 256) {
        int r = eidx(ei, is64, e);
        int c = eidx(ei, is64, N_EDGES + e);
        float w = ew[e];
        int b = c >> BSH;
        int off = atomicAdd(&lcur[b], 1);
        abuf[lbase[b] + off] = make_uint2((unsigned)r | ((unsigned)(c & (BNODES - 1)) << 17),
                                          __float_as_uint(w));
    }
}

__global__ __launch_bounds__(256)
void k_bsortC(const int* __restrict__ bstart, const uint2* __restrict__ abuf,
              uint2* __restrict__ eperm, int* __restrict__ startA,
              int* __restrict__ cntA, float* __restrict__ dinv) {
    __shared__ uint2 se[BCAP];
    __shared__ int   cnt[BNODES];
    __shared__ int   scn[256];
    __shared__ int   cur[BNODES];
    __shared__ float wsum[BNODES];
    int t = threadIdx.x, b = blockIdx.x;
    int s0 = bstart[b], s1 = bstart[b + 1];
    int nb = s1 - s0;
    if (t < BNODES) { cnt[t] = 0; wsum[t] = 0.0f; }
    __syncthreads();
    bool fits = (nb <= BCAP);
    if (fits) {
        for (int k = t; k < nb; k += 256) {
            uint2 a = abuf[s0 + k];
            se[k] = a;
            int ln = (int)(a.x >> 17);
            atomicAdd(&cnt[ln], 1);
            atomicAdd(&wsum[ln], __uint_as_float(a.y));
        }
    } else {
        for (int k = t; k < nb; k += 256) {
            uint2 a = abuf[s0 + k];
            int ln = (int)(a.x >> 17);
            atomicAdd(&cnt[ln], 1);
            atomicAdd(&wsum[ln], __uint_as_float(a.y));
        }
    }
    __syncthreads();
    int v = (t < BNODES) ? cnt[t] : 0;
    scn[t] = v;
    __syncthreads();
    for (int off = 1; off < 256; off <<= 1) {
        int u = (t >= off) ? scn[t - off] : 0;
        __syncthreads();
        scn[t] += u;
        __syncthreads();
    }
    int excl = scn[t] - v;
    if (t < BNODES) {
        cur[t] = excl;
        int node = b * BNODES + t;
        if (node < N_NODES) {
            startA[node] = s0 + excl;
            cntA[node]   = cnt[t];
            dinv[node]   = rsqrtf(1.0f + wsum[t]);
        }
    }
    __syncthreads();
    if (fits) {
        for (int k = t; k < nb; k += 256) {
            uint2 a = se[k];
            int ln = (int)(a.x >> 17);
            int off = atomicAdd(&cur[ln], 1);
            eperm[s0 + off] = make_uint2(a.x & 0x1FFFFu, a.y);
        }
    } else {
        for (int k = t; k < nb; k += 256) {
            uint2 a = abuf[s0 + k];
            int ln = (int)(a.x >> 17);
            int off = atomicAdd(&cur[ln], 1);
            eperm[s0 + off] = make_uint2(a.x & 0x1FFFFu, a.y);
        }
    }
}

// ---------- gather layer 1 (+ bias + self-loop) fused with gemm2 ----------

__global__ __launch_bounds__(256)
void k_gather1(const int* __restrict__ startA, const int* __restrict__ cntA,
               const uint2* __restrict__ ep, const float* __restrict__ dinv,
               const unsigned short* __restrict__ h1b, const float* __restrict__ b1,
               const float* __restrict__ W2g, float* __restrict__ x1,
               unsigned short* __restrict__ h2b) {
    __shared__ float sW2[HIDDEN * NCLS];
    __shared__ float sv[16][HIDDEN + 1];
    int t = threadIdx.x;
    if (t < HIDDEN * NCLS) sW2[t] = W2g[t];
    int ln = t >> 4, es = (t >> 2) & 3, fs = t & 3;
    int i = blockIdx.x * 16 + ln;
    bool act = (i < N_NODES);
    float4 a = make_float4(0.0f, 0.0f, 0.0f, 0.0f);
    float4 b = make_float4(0.0f, 0.0f, 0.0f, 0.0f);
    if (act) {
        int s0 = startA[i], n = cntA[i];
        int k = es;
        for (; k + 4 < n; k += 8) {
            uint2 e0 = ep[s0 + k];
            uint2 e1 = ep[s0 + k + 4];
            int r0 = (int)e0.x, r1 = (int)e1.x;
            float w0 = __uint_as_float(e0.y) * dinv[r0];
            float w1 = __uint_as_float(e1.y) * dinv[r1];
            uint2 p0 = *(const uint2*)(h1b + ((size_t)r0 << 4) + 4 * fs);
            uint2 p1 = *(const uint2*)(h1b + ((size_t)r1 << 4) + 4 * fs);
            a.x = fmaf(w0, __uint_as_float(p0.x << 16),          a.x);
            a.y = fmaf(w0, __uint_as_float(p0.x & 0xFFFF0000u),  a.y);
            a.z = fmaf(w0, __uint_as_float(p0.y << 16),          a.z);
            a.w = fmaf(w0, __uint_as_float(p0.y & 0xFFFF0000u),  a.w);
            b.x = fmaf(w1, __uint_as_float(p1.x << 16),          b.x);
            b.y = fmaf(w1, __uint_as_float(p1.x & 0xFFFF0000u),  b.y);
            b.z = fmaf(w1, __uint_as_float(p1.y << 16),          b.z);
            b.w = fmaf(w1, __uint_as_float(p1.y & 0xFFFF0000u),  b.w);
        }
        if (k < n) {
            uint2 e0 = ep[s0 + k];
            int r0 = (int)e0.x;
            float w0 = __uint_as_float(e0.y) * dinv[r0];
            uint2 p0 = *(const uint2*)(h1b + ((size_t)r0 << 4) + 4 * fs);
            a.x = fmaf(w0, __uint_as_float(p0.x << 16),          a.x);
            a.y = fmaf(w0, __uint_as_float(p0.x & 0xFFFF0000u),  a.y);
            a.z = fmaf(w0, __uint_as_float(p0.y << 16),          a.z);
            a.w = fmaf(w0, __uint_as_float(p0.y & 0xFFFF0000u),  a.w);
        }
    }
    a.x += b.x; a.y += b.y; a.z += b.z; a.w += b.w;
    a.x += __shfl_xor(a.x, 4); a.y += __shfl_xor(a.y, 4);
    a.z += __shfl_xor(a.z, 4); a.w += __shfl_xor(a.w, 4);
    a.x += __shfl_xor(a.x, 8); a.y += __shfl_xor(a.y, 8);
    a.z += __shfl_xor(a.z, 8); a.w += __shfl_xor(a.w, 8);
    if (act && es == 0) {
        float di = dinv[i], d2 = di * di;
        uint2 ps = *(const uint2*)(h1b + ((size_t)i << 4) + 4 * fs);
        const float* b1r = b1 + 4 * fs;
        float v0 = di * a.x + d2 * __uint_as_float(ps.x << 16)         + b1r[0];
        float v1 = di * a.y + d2 * __uint_as_float(ps.x & 0xFFFF0000u) + b1r[1];
        float v2 = di * a.z + d2 * __uint_as_float(ps.y << 16)         + b1r[2];
        float v3 = di * a.w + d2 * __uint_as_float(ps.y & 0xFFFF0000u) + b1r[3];
        *(float4*)(x1 + (size_t)i * HIDDEN + 4 * fs) = make_float4(v0, v1, v2, v3);
        sv[ln][4 * fs + 0] = v0; sv[ln][4 * fs + 1] = v1;
        sv[ln][4 * fs + 2] = v2; sv[ln][4 * fs + 3] = v3;
    }
    __syncthreads();
    int j = t & 15;
    if (act && j < 8) {
        float acc2 = 0.0f;
        if (j < NCLS) {
#pragma unroll
            for (int kk = 0; kk < HIDDEN; ++kk)
                acc2 = fmaf(sv[ln][kk], sW2[kk * NCLS + j], acc2);
        }
        h2b[(size_t)i * 8 + j] = (j < NCLS) ? f2bf(acc2) : (unsigned short)0;
    }
}

// ---------- gather layer 2 fused with log_softmax ----------

__global__ __launch_bounds__(256)
void k_gather2(const int* __restrict__ startA, const int* __restrict__ cntA,
               const uint2* __restrict__ ep, const float* __restrict__ dinv,
               const unsigned short* __restrict__ h2b, const float* __restrict__ b2,
               float* __restrict__ out) {
    __shared__ float sv[16][9];
    int t = threadIdx.x;
    int ln = t >> 4, es = (t >> 1) & 7, fs = t & 1;
    int i = blockIdx.x * 16 + ln;
    bool act = (i < N_NODES);
    float4 a = make_float4(0.0f, 0.0f, 0.0f, 0.0f);
    float4 b = make_float4(0.0f, 0.0f, 0.0f, 0.0f);
    if (act) {
        int s0 = startA[i], n = cntA[i];
        int k = es;
        for (; k + 8 < n; k += 16) {
            uint2 e0 = ep[s0 + k];
            uint2 e1 = ep[s0 + k + 8];
            int r0 = (int)e0.x, r1 = (int)e1.x;
            float w0 = __uint_as_float(e0.y) * dinv[r0];
            float w1 = __uint_as_float(e1.y) * dinv[r1];
            uint2 p0 = *(const uint2*)(h2b + ((size_t)r0 << 3) + 4 * fs);
            uint2 p1 = *(const uint2*)(h2b + ((size_t)r1 << 3) + 4 * fs);
            a.x = fmaf(w0, __uint_as_float(p0.x << 16),          a.x);
            a.y = fmaf(w0, __uint_as_float(p0.x & 0xFFFF0000u),  a.y);
            a.z = fmaf(w0, __uint_as_float(p0.y << 16),          a.z);
            a.w = fmaf(w0, __uint_as_float(p0.y & 0xFFFF0000u),  a.w);
            b.x = fmaf(w1, __uint_as_float(p1.x << 16),          b.x);
            b.y = fmaf(w1, __uint_as_float(p1.x & 0xFFFF0000u),  b.y);
            b.z = fmaf(w1, __uint_as_float(p1.y << 16),          b.z);
            b.w = fmaf(w1, __uint_as_float(p1.y & 0xFFFF0000u),  b.w);
        }
        if (k < n) {
            uint2 e0 = ep[s0 + k];
            int r0 = (int)e0.x;
            float w0 = __uint_as_float(e0.y) * dinv[r0];
            uint2 p0 = *(const uint2*)(h2b + ((size_t)r0 << 3) + 4 * fs);
            a.x = fmaf(w0, __uint_as_float(p0.x << 16),          a.x);
            a.y = fmaf(w0, __uint_as_float(p0.x & 0xFFFF0000u),  a.y);
            a.z = fmaf(w0, __uint_as_float(p0.y << 16),          a.z);
            a.w = fmaf(w0, __uint_as_float(p0.y & 0xFFFF0000u),  a.w);
        }
    }
    a.x += b.x; a.y += b.y; a.z += b.z; a.w += b.w;
    a.x += __shfl_xor(a.x, 2); a.y += __shfl_xor(a.y, 2);
    a.z += __shfl_xor(a.z, 2); a.w += __shfl_xor(a.w, 2);
    a.x += __shfl_xor(a.x, 4); a.y += __shfl_xor(a.y, 4);
    a.z += __shfl_xor(a.z, 4); a.w += __shfl_xor(a.w, 4);
    a.x += __shfl_xor(a.x, 8); a.y += __shfl_xor(a.y, 8);
    a.z += __shfl_xor(a.z, 8); a.w += __shfl_xor(a.w, 8);
    if (act && es == 0) {
        float di = dinv[i], d2 = di * di;
        uint2 ps = *(const uint2*)(h2b + ((size_t)i << 3) + 4 * fs);
        int c0 = 4 * fs;
        float s0v = __uint_as_float(ps.x << 16);
        float s1v = __uint_as_float(ps.x & 0xFFFF0000u);
        float s2v = __uint_as_float(ps.y << 16);
        float s3v = __uint_as_float(ps.y & 0xFFFF0000u);
        float v0 = di * a.x + d2 * s0v + ((c0 + 0) < NCLS ? b2[c0 + 0] : 0.0f);
        float v1 = di * a.y + d2 * s1v + ((c0 + 1) < NCLS ? b2[c0 + 1] : 0.0f);
        float v2 = di * a.z + d2 * s2v + ((c0 + 2) < NCLS ? b2[c0 + 2] : 0.0f);
        float v3 = di * a.w + d2 * s3v + ((c0 + 3) < NCLS ? b2[c0 + 3] : 0.0f);
        sv[ln][c0 + 0] = v0; sv[ln][c0 + 1] = v1;
        sv[ln][c0 + 2] = v2; sv[ln][c0 + 3] = v3;
    }
    __syncthreads();
    int j = t & 15;
    if (act && j < NCLS) {
        float m = -1e30f;
#pragma unroll
        for (int c = 0; c < NCLS; ++c) m = fmaxf(m, sv[ln][c]);
        float ssum = 0.0f;
#pragma unroll
        for (int c = 0; c < NCLS; ++c) ssum += __expf(sv[ln][c] - m);
        out[(size_t)i * NCLS + j] = sv[ln][j] - m - __logf(ssum);
    }
}

// ---------- tier-3 atomic fallback kernels (small ws) ----------

__global__ void k_initdeg(float* __restrict__ deg) {
    int i = blockIdx.x * 256 + threadIdx.x;
    if (i < N_NODES) deg[i] = 1.0f;
}

__global__ void k_degacc(const int* __restrict__ ei, const float* __restrict__ w,
                         const int* __restrict__ flag, float* __restrict__ deg) {
    int e = blockIdx.x * 256 + threadIdx.x;
    if (e >= N_EDGES) return;
    int c = eidx(ei, flag[0], N_EDGES + e);
    atomicAdd(&deg[c], w[e]);
}

__global__ void k_dinv(float* __restrict__ deg) {
    int i = blockIdx.x * 256 + threadIdx.x;
    if (i < N_NODES) {
        float d = deg[i];
        deg[i] = (d > 0.0f) ? rsqrtf(d) : 0.0f;
    }
}

__global__ __launch_bounds__(256)
void k_gemm1f(const float* __restrict__ x, const float* __restrict__ W1g,
              float* __restrict__ h1) {
    __shared__ float w1s[D_FEAT * HIDDEN];
    for (int p = threadIdx.x; p < D_FEAT * HIDDEN; p += 256) w1s[p] = W1g[p];
    __syncthreads();
    const int total = N_NODES * HIDDEN;
    for (int t = blockIdx.x * 256 + threadIdx.x; t < total; t += gridDim.x * 256) {
        int i = t >> 4, j = t & 15;
        const float4* xr = (const float4*)(x + (size_t)i * D_FEAT);
        float acc = 0.0f;
#pragma unroll 4
        for (int k4 = 0; k4 < D_FEAT / 4; ++k4) {
            float4 xv = xr[k4];
            int kb = (k4 << 6) + j;
            acc = fmaf(xv.x, w1s[kb],      acc);
            acc = fmaf(xv.y, w1s[kb + 16], acc);
            acc = fmaf(xv.z, w1s[kb + 32], acc);
            acc = fmaf(xv.w, w1s[kb + 48], acc);
        }
        h1[t] = acc;
    }
}

__global__ __launch_bounds__(256)
void k_scatter1(const int* __restrict__ ei, const float* __restrict__ w,
                const int* __restrict__ flag, const float* __restrict__ dinv,
                const float* __restrict__ h1, float* __restrict__ agg1) {
    int t = blockIdx.x * 256 + threadIdx.x;
    if (t >= N_EDGES * HIDDEN) return;
    int e = t >> 4, j = t & 15;
    int is64 = flag[0];
    int r = eidx(ei, is64, e);
    int c = eidx(ei, is64, N_EDGES + e);
    float nrm = dinv[r] * w[e] * dinv[c];
    atomicAdd(&agg1[(size_t)c * HIDDEN + j], nrm * h1[(size_t)r * HIDDEN + j]);
}

__global__ void k_fin1_gemm2(const float* __restrict__ b1, const float* __restrict__ W2,
                             const float* __restrict__ dinv, const float* __restrict__ h1,
                             float* __restrict__ x1, float* __restrict__ h2) {
    int i = blockIdx.x * 256 + threadIdx.x;
    if (i >= N_NODES) return;
    float d2 = dinv[i] * dinv[i];
    float v[HIDDEN];
#pragma unroll
    for (int k = 0; k < HIDDEN; ++k)
        v[k] = x1[(size_t)i * HIDDEN + k] + d2 * h1[(size_t)i * HIDDEN + k] + b1[k];
#pragma unroll
    for (int k = 0; k < HIDDEN; ++k)
        x1[(size_t)i * HIDDEN + k] = v[k];
#pragma unroll
    for (int j = 0; j < NCLS; ++j) {
        float a = 0.0f;
#pragma unroll
        for (int k = 0; k < HIDDEN; ++k) a = fmaf(v[k], W2[k * NCLS + j], a);
        h2[(size_t)i * NCLS + j] = a;
    }
}

__global__ __launch_bounds__(256)
void k_scatter2(const int* __restrict__ ei, const float* __restrict__ w,
                const int* __restrict__ flag, const float* __restrict__ dinv,
                const float* __restrict__ h2, float* __restrict__ agg2) {
    int t = blockIdx.x * 256 + threadIdx.x;
    if (t >= N_EDGES * NCLS) return;
    int e = t / NCLS, j = t - e * NCLS;
    int is64 = flag[0];
    int r = eidx(ei, is64, e);
    int c = eidx(ei, is64, N_EDGES + e);
    float nrm = dinv[r] * w[e] * dinv[c];
    atomicAdd(&agg2[(size_t)c * NCLS + j], nrm * h2[(size_t)r * NCLS + j]);
}

__global__ void k_final(const float* __restrict__ agg2, const float* __restrict__ h2,
                        const float* __restrict__ dinv, const float* __restrict__ b2,
                        float* __restrict__ out) {
    int i = blockIdx.x * 256 + threadIdx.x;
    if (i >= N_NODES) return;
    float d2 = dinv[i] * dinv[i];
    float v[NCLS];
    float m = -1e30f;
#pragma unroll
    for (int j = 0; j < NCLS; ++j) {
        v[j] = agg2[(size_t)i * NCLS + j] + d2 * h2[(size_t)i * NCLS + j] + b2[j];
        m = fmaxf(m, v[j]);
    }
    float s = 0.0f;
#pragma unroll
    for (int j = 0; j < NCLS; ++j) s += __expf(v[j] - m);
    float l = __logf(s);
#pragma unroll
    for (int j = 0; j < NCLS; ++j) out[(size_t)i * NCLS + j] = v[j] - m - l;
}

// ---------- launch ----------

extern "C" void kernel_launch(void* const* d_in, const int* in_sizes, int n_in,
                              void* d_out, int out_size, void* d_ws, size_t ws_size,
                              hipStream_t stream) {
    const float* x  = (const float*)d_in[0];
    const float* W1 = (const float*)d_in[1];
    const float* b1 = (const float*)d_in[2];
    const float* W2 = (const float*)d_in[3];
    const float* b2 = (const float*)d_in[4];
    const float* ew = (const float*)d_in[5];
    const int*   ei = (const int*)d_in[6];

    float* out = (float*)d_out;
    float* lsm = out;                               // [N, 6]
    float* x1  = out + (size_t)N_NODES * NCLS;      // [N, 16]

    const int NB_N = (N_NODES + 255) / 256;
    const int NB_E = (N_EDGES + 255) / 256;

    float* W    = (float*)d_ws;
    int*   flag = (int*)d_ws;

    // ---- tier-1 layout (4B words), fixed-cap buckets ----
    int*   bcursor1 = (int*)(W + 0);          // 782
    int*   startA1  = (int*)(W + 1024);       // 100000
    int*   cntA1    = (int*)(W + 101024);     // 100000
    float* dinv1    = W + 201024;             // 100000
    unsigned short* h1b1 = (unsigned short*)(W + 301056);  // 800000 words
    unsigned short* h2b1 = (unsigned short*)(W + 1101056); // 400000 words
    uint2* abuf1    = (uint2*)(W + 1501056);  // 782*8192 uint2 = 12812288 words
    uint2* eperm1   = (uint2*)(W + 14313344); // 12812288 words -> ends 27125632
    const size_t NEED1 = (size_t)27125632 * 4;      // ~108.5 MB

    // ---- tier-2 layout (contiguous, ~52.4 MB) ----
    int*   bcnt2    = (int*)(W + 256);
    int*   bstart2  = (int*)(W + 1152);
    int*   bcursor2 = (int*)(W + 2048);
    int*   startA2  = (int*)(W + 2944);       // 100001
    float* dinv2    = W + 102948;
    uint2* abuf2    = (uint2*)(W + 202948);   // aliased with h1b2/h2b2 after bsort
    unsigned short* h1b2 = (unsigned short*)(W + 202948);
    unsigned short* h2b2 = (unsigned short*)(W + 1802948);
    uint2* eperm2   = (uint2*)(W + 6602948);
    int*   cntA2    = (int*)(W + 13002948);   // 100000 -> ends 13102948
    const size_t NEED2 = (size_t)13102948 * 4;      // ~52.4 MB

    if (ws_size >= NEED1) {
        hipMemsetAsync(bcursor1, 0, NBUK * 4, stream);
        k_buildA<<<NBLK_A + NGEMM, 256, 0, stream>>>(ei, ew, bcursor1, abuf1,
                                                     x, W1, h1b1);
        k_bsortF<<<NBUK, 256, 0, stream>>>(bcursor1, abuf1, eperm1,
                                           startA1, cntA1, dinv1);
        k_gather1<<<(N_NODES + 15) / 16, 256, 0, stream>>>(startA1, cntA1, eperm1,
                                                           dinv1, h1b1, b1, W2,
                                                           x1, h2b1);
        k_gather2<<<(N_NODES + 15) / 16, 256, 0, stream>>>(startA1, cntA1, eperm1,
                                                           dinv1, h2b1, b2, lsm);
    } else if (ws_size >= NEED2) {
        hipMemsetAsync(bcnt2, 0, (NBUK + 1) * 4, stream);
        k_detect<<<1, 64, 0, stream>>>(ei, flag);
        k_bhist <<<NBLK_A, 256, 0, stream>>>(ei, flag, bcnt2);
        k_bscan <<<1, 1024, 0, stream>>>(bcnt2, bstart2, bcursor2);
        k_bscat <<<NBLK_A, 256, 0, stream>>>(ei, ew, flag, bcursor2, abuf2);
        k_bsortC<<<NBUK, 256, 0, stream>>>(bstart2, abuf2, eperm2,
                                           startA2, cntA2, dinv2);
        k_gemm1 <<<NGEMM, 256, 0, stream>>>(x, W1, h1b2);
        k_gather1<<<(N_NODES + 15) / 16, 256, 0, stream>>>(startA2, cntA2, eperm2,
                                                           dinv2, h1b2, b1, W2,
                                                           x1, h2b2);
        k_gather2<<<(N_NODES + 15) / 16, 256, 0, stream>>>(startA2, cntA2, eperm2,
                                                           dinv2, h2b2, b2, lsm);
    } else {
        float* deg  = W + 1024;
        float* fh1  = W + 101376;
        float* fh2  = fh1 + (size_t)N_NODES * HIDDEN;
        float* agg2 = fh2 + (size_t)N_NODES * NCLS;
        hipMemsetAsync(x1,   0, (size_t)N_NODES * HIDDEN * sizeof(float), stream);
        hipMemsetAsync(agg2, 0, (size_t)N_NODES * NCLS   * sizeof(float), stream);
        k_detect <<<1, 64, 0, stream>>>(ei, flag);
        k_initdeg<<<NB_N, 256, 0, stream>>>(deg);
        k_degacc <<<NB_E, 256, 0, stream>>>(ei, ew, flag, deg);
        k_dinv   <<<NB_N, 256, 0, stream>>>(deg);
        k_gemm1f <<<2048, 256, 0, stream>>>(x, W1, fh1);
        k_scatter1<<<(N_EDGES * HIDDEN + 255) / 256, 256, 0, stream>>>(ei, ew, flag, deg, fh1, x1);
        k_fin1_gemm2<<<NB_N, 256, 0, stream>>>(b1, W2, deg, fh1, x1, fh2);
        k_scatter2<<<(N_EDGES * NCLS + 255) / 256, 256, 0, stream>>>(ei, ew, flag, deg, fh2, agg2);
        k_final  <<<NB_N, 256, 0, stream>>>(agg2, fh2, deg, b2, lsm);
    }
}